// Round 1
// baseline (918.094 us; speedup 1.0000x reference)
//
#include <hip/hip_runtime.h>

// y[b, i] = sum_nnz v * x[b, j] + biases[i]
// Block structure: 320k edges, each a 4x4 dense block at (4r, 4c);
// values contiguous per edge (row-major 4x4).

__global__ void hist_kernel(const int* __restrict__ indices, int* __restrict__ cnt, int E) {
  int e = blockIdx.x * blockDim.x + threadIdx.x;
  if (e >= E) return;
  int bi = indices[(size_t)e * 32];  // first entry of edge e: (bi, bj)
  atomicAdd(&cnt[bi >> 2], 1);
}

__global__ void scan_kernel(const int* __restrict__ cnt, int* __restrict__ row_start, int n) {
  __shared__ int buf[1024];
  __shared__ int carry_s;
  int t = threadIdx.x;
  if (t == 0) { carry_s = 0; row_start[0] = 0; }
  __syncthreads();
  for (int base = 0; base < n; base += 1024) {
    int v = (base + t < n) ? cnt[base + t] : 0;
    buf[t] = v;
    __syncthreads();
    for (int off = 1; off < 1024; off <<= 1) {
      int add = (t >= off) ? buf[t - off] : 0;
      __syncthreads();
      buf[t] += add;
      __syncthreads();
    }
    if (base + t < n) row_start[base + t + 1] = buf[t] + carry_s;
    __syncthreads();
    if (t == 0) carry_s += buf[1023];
    __syncthreads();
  }
}

__global__ void scatter_kernel(const int* __restrict__ indices, const int* __restrict__ row_start,
                               int* __restrict__ cursor, int2* __restrict__ edge_list, int E) {
  int e = blockIdx.x * blockDim.x + threadIdx.x;
  if (e >= E) return;
  int bi = indices[(size_t)e * 32];
  int bj = indices[(size_t)e * 32 + 1];
  int r = bi >> 2, c = bj >> 2;
  int pos = atomicAdd(&cursor[r], 1);
  edge_list[row_start[r] + pos] = make_int2(c, e);
}

__global__ void reorder_kernel(const int2* __restrict__ edge_list, const float* __restrict__ vals,
                               float* __restrict__ vals_sorted, int* __restrict__ col_sorted, int E) {
  int tid = blockIdx.x * blockDim.x + threadIdx.x;
  int p = tid >> 4;  // sorted slot
  int i = tid & 15;
  if (p >= E) return;
  int2 ce = edge_list[p];
  vals_sorted[(size_t)p * 16 + i] = vals[(size_t)ce.y * 16 + i];
  if (i == 0) col_sorted[p] = ce.x;
}

// in[rows][cols] -> out[cols][rows]
__global__ void transpose_kernel(const float* __restrict__ in, float* __restrict__ out,
                                 int rows, int cols) {
  __shared__ float tile[64][65];
  int c0 = blockIdx.x * 64;
  int r0 = blockIdx.y * 64;
  int tx = threadIdx.x & 63, ty = threadIdx.x >> 6;
#pragma unroll
  for (int k = 0; k < 64; k += 4) {
    int r = r0 + ty + k, c = c0 + tx;
    if (r < rows && c < cols) tile[ty + k][tx] = in[(size_t)r * cols + c];
  }
  __syncthreads();
#pragma unroll
  for (int k = 0; k < 64; k += 4) {
    int c = c0 + ty + k, r = r0 + tx;
    if (r < rows && c < cols) out[(size_t)c * rows + r] = tile[tx][ty + k];
  }
}

// Main SpMM: one block = (block-row r, batch chunk of 256). acc[4] per thread.
template <bool USE_XT>
__global__ __launch_bounds__(256) void spmm_kernel(
    const int* __restrict__ row_start, const int* __restrict__ col_sorted,
    const float* __restrict__ vals_sorted, const float* __restrict__ xsrc,
    const float* __restrict__ biases, float* __restrict__ out,
    int n_nodes, int batch, int size) {
  int nx = gridDim.x;
  int bx = blockIdx.x;
  // XCD-bijective swizzle: consecutive r on the same XCD -> partial-line out
  // writes merge in that XCD's L2. Valid since grid.x % 8 == 0 (guarded).
  int r = ((nx & 7) == 0) ? ((bx & 7) * (nx >> 3) + (bx >> 3)) : bx;
  int b = blockIdx.y * blockDim.x + threadIdx.x;
  int s = row_start[r];
  int e = row_start[r + 1];
  float a0 = 0.f, a1 = 0.f, a2 = 0.f, a3 = 0.f;
  for (int p = s; p < e; ++p) {
    int c = col_sorted[p];                       // wave-uniform -> s_load
    const float* V = vals_sorted + (size_t)p * 16;  // wave-uniform, sequential
    float x0, x1, x2, x3;
    if (USE_XT) {
      const float* xc = xsrc + (size_t)(c << 2) * batch + b;  // coalesced dwords
      x0 = xc[0];
      x1 = xc[batch];
      x2 = xc[2 * batch];
      x3 = xc[3 * batch];
    } else {
      const float4 xv = *(const float4*)(xsrc + (size_t)b * size + (c << 2));
      x0 = xv.x; x1 = xv.y; x2 = xv.z; x3 = xv.w;
    }
    a0 += V[0] * x0 + V[1] * x1 + V[2] * x2 + V[3] * x3;
    a1 += V[4] * x0 + V[5] * x1 + V[6] * x2 + V[7] * x3;
    a2 += V[8] * x0 + V[9] * x1 + V[10] * x2 + V[11] * x3;
    a3 += V[12] * x0 + V[13] * x1 + V[14] * x2 + V[15] * x3;
  }
  float4 bias = *(const float4*)&biases[r << 2];
  float4 o = make_float4(a0 + bias.x, a1 + bias.y, a2 + bias.z, a3 + bias.w);
  *(float4*)&out[(size_t)b * size + (r << 2)] = o;
}

// Last-resort fallback (tiny ws): bias init + per-entry atomics. Slow but correct.
__global__ void bias_init_kernel(float* __restrict__ out, const float* __restrict__ biases,
                                 int batch, int size) {
  size_t t = (size_t)blockIdx.x * blockDim.x + threadIdx.x;
  size_t total = (size_t)batch * size;
  if (t >= total) return;
  out[t] = biases[t % size];
}

__global__ void atomic_spmm_kernel(const int* __restrict__ indices, const float* __restrict__ vals,
                                   const float* __restrict__ x, float* __restrict__ out,
                                   int nnz, int batch, int size) {
  // one block per nnz entry; threads cover batch
  int n = blockIdx.x;
  if (n >= nnz) return;
  int i = indices[(size_t)n * 2];
  int j = indices[(size_t)n * 2 + 1];
  float v = vals[n];
  for (int b = threadIdx.x; b < batch; b += blockDim.x) {
    atomicAdd(&out[(size_t)b * size + i], v * x[(size_t)b * size + j]);
  }
}

extern "C" void kernel_launch(void* const* d_in, const int* in_sizes, int n_in,
                              void* d_out, int out_size, void* d_ws, size_t ws_size,
                              hipStream_t stream) {
  const float* x      = (const float*)d_in[0];
  const float* values = (const float*)d_in[1];
  const float* biases = (const float*)d_in[2];
  const int*   indices = (const int*)d_in[3];
  float* out = (float*)d_out;

  const int size    = in_sizes[2];        // 40000
  const int nnz     = in_sizes[1];        // 5,120,000
  const int batch   = in_sizes[0] / size; // 1024
  const int E       = nnz / 16;           // 320,000
  const int n_nodes = size / 4;           // 10,000

  // ---- workspace layout ----
  char* ws = (char*)d_ws;
  size_t off = 0;
  int* cnt = (int*)(ws + off);        off += (size_t)n_nodes * 4;
  int* cursor = (int*)(ws + off);     off += (size_t)n_nodes * 4;
  int* row_start = (int*)(ws + off);  off += ((size_t)n_nodes + 1) * 4;
  off = (off + 255) & ~(size_t)255;
  int* col_sorted = (int*)(ws + off); off += (size_t)E * 4;
  off = (off + 255) & ~(size_t)255;
  int2* edge_list = (int2*)(ws + off); off += (size_t)E * 8;
  off = (off + 255) & ~(size_t)255;
  float* vals_sorted = (float*)(ws + off); off += (size_t)E * 64;
  off = (off + 255) & ~(size_t)255;
  size_t need_csr = off;
  float* xT = (float*)(ws + off); off += (size_t)size * batch * 4;
  size_t need_full = off;

  if (ws_size >= need_csr) {
    hipMemsetAsync(cnt, 0, (size_t)2 * n_nodes * 4, stream);
    hist_kernel<<<(E + 255) / 256, 256, 0, stream>>>(indices, cnt, E);
    scan_kernel<<<1, 1024, 0, stream>>>(cnt, row_start, n_nodes);
    scatter_kernel<<<(E + 255) / 256, 256, 0, stream>>>(indices, row_start, cursor, edge_list, E);
    reorder_kernel<<<((size_t)E * 16 + 255) / 256, 256, 0, stream>>>(edge_list, values, vals_sorted, col_sorted, E);

    dim3 grid(n_nodes, batch / 256);
    if (ws_size >= need_full) {
      transpose_kernel<<<dim3((size + 63) / 64, (batch + 63) / 64), 256, 0, stream>>>(x, xT, batch, size);
      spmm_kernel<true><<<grid, 256, 0, stream>>>(row_start, col_sorted, vals_sorted, xT,
                                                  biases, out, n_nodes, batch, size);
    } else {
      spmm_kernel<false><<<grid, 256, 0, stream>>>(row_start, col_sorted, vals_sorted, x,
                                                   biases, out, n_nodes, batch, size);
    }
  } else {
    // tiny workspace fallback: correct but slow
    size_t total = (size_t)batch * size;
    bias_init_kernel<<<(total + 255) / 256, 256, 0, stream>>>(out, biases, batch, size);
    atomic_spmm_kernel<<<nnz, 256, 0, stream>>>(indices, values, x, out, nnz, batch, size);
  }
}

// Round 2
// 538.624 us; speedup vs baseline: 1.7045x; 1.7045x over previous
//
#include <hip/hip_runtime.h>

// y[b, i] = sum v * x[b, j] + biases[i]
// 320k edges, each a dense 4x4 block at (4r, 4c); values row-major per edge.
// Strategy: build CSR per launch, reorder vals, pack x into bf16 [node][batch][4],
// then one gather-FMA kernel with 4 block-rows per block (full-line writes).

__device__ __forceinline__ unsigned short f2bf_rne(float f) {
  union { float f; unsigned u; } v; v.f = f;
  unsigned r = (v.u + 0x7fffu + ((v.u >> 16) & 1u)) >> 16;
  return (unsigned short)r;
}

__global__ void hist_kernel(const int* __restrict__ indices, int* __restrict__ cnt, int E) {
  int e = blockIdx.x * blockDim.x + threadIdx.x;
  if (e >= E) return;
  int bi = indices[(size_t)e * 32];
  atomicAdd(&cnt[bi >> 2], 1);
}

__global__ void scan_kernel(const int* __restrict__ cnt, int* __restrict__ row_start, int n) {
  __shared__ int buf[1024];
  __shared__ int carry_s;
  int t = threadIdx.x;
  if (t == 0) { carry_s = 0; row_start[0] = 0; }
  __syncthreads();
  for (int base = 0; base < n; base += 1024) {
    int v = (base + t < n) ? cnt[base + t] : 0;
    buf[t] = v;
    __syncthreads();
    for (int off = 1; off < 1024; off <<= 1) {
      int add = (t >= off) ? buf[t - off] : 0;
      __syncthreads();
      buf[t] += add;
      __syncthreads();
    }
    if (base + t < n) row_start[base + t + 1] = buf[t] + carry_s;
    __syncthreads();
    if (t == 0) carry_s += buf[1023];
    __syncthreads();
  }
}

__global__ void scatter_kernel(const int* __restrict__ indices, const int* __restrict__ row_start,
                               int* __restrict__ cursor, int2* __restrict__ edge_list, int E) {
  int e = blockIdx.x * blockDim.x + threadIdx.x;
  if (e >= E) return;
  int bi = indices[(size_t)e * 32];
  int bj = indices[(size_t)e * 32 + 1];
  int r = bi >> 2, c = bj >> 2;
  int pos = atomicAdd(&cursor[r], 1);
  edge_list[row_start[r] + pos] = make_int2(c, e);
}

__global__ void reorder_kernel(const int2* __restrict__ edge_list, const float* __restrict__ vals,
                               float* __restrict__ vals_sorted, int* __restrict__ col_sorted, int E) {
  int tid = blockIdx.x * blockDim.x + threadIdx.x;
  int p = tid >> 4;
  int i = tid & 15;
  if (p >= E) return;
  int2 ce = edge_list[p];
  vals_sorted[(size_t)p * 16 + i] = vals[(size_t)ce.y * 16 + i];
  if (i == 0) col_sorted[p] = ce.x;
}

// x[b][4c+k] (fp32) -> xb[((c*batch)+b)*4 + k] (bf16 packed per node)
__global__ void pack_bf16_kernel(const float* __restrict__ in, unsigned short* __restrict__ out,
                                 int batch, int size) {
  __shared__ float tile[64][65];
  int c0 = blockIdx.x * 64;  // column (size dim) base
  int b0 = blockIdx.y * 64;  // batch base
  int tx = threadIdx.x & 63, ty = threadIdx.x >> 6;
#pragma unroll
  for (int k = 0; k < 64; k += 4) {
    int b = b0 + ty + k, c = c0 + tx;
    if (b < batch && c < size) tile[ty + k][tx] = in[(size_t)b * size + c];
  }
  __syncthreads();
  // 16 nodes x 64 batch entries = 1024 outputs of 8B; 256 threads -> 4 iters
#pragma unroll
  for (int it = 0; it < 4; ++it) {
    int idx = it * 256 + threadIdx.x;
    int cn_local = idx >> 6;   // 0..15
    int bl = idx & 63;
    int c_node = (c0 >> 2) + cn_local;
    int b = b0 + bl;
    if (b < batch && (c_node * 4 + 3) < size) {
      unsigned short u0 = f2bf_rne(tile[bl][cn_local * 4 + 0]);
      unsigned short u1 = f2bf_rne(tile[bl][cn_local * 4 + 1]);
      unsigned short u2 = f2bf_rne(tile[bl][cn_local * 4 + 2]);
      unsigned short u3 = f2bf_rne(tile[bl][cn_local * 4 + 3]);
      uint2 packed = make_uint2((unsigned)u0 | ((unsigned)u1 << 16),
                                (unsigned)u2 | ((unsigned)u3 << 16));
      *(uint2*)&out[((size_t)c_node * batch + b) * 4] = packed;
    }
  }
}

__device__ __forceinline__ float bf_lo(unsigned u) {
  union { unsigned u; float f; } v; v.u = u << 16; return v.f;
}
__device__ __forceinline__ float bf_hi(unsigned u) {
  union { unsigned u; float f; } v; v.u = u & 0xffff0000u; return v.f;
}

// MODE 0: packed bf16 gather. MODE 1: direct fp32 x [batch][size] gather.
// One block = (4 block-rows, 256-batch chunk). Lane writes 64B contiguous.
template <int MODE>
__global__ __launch_bounds__(256) void spmm_kernel(
    const int* __restrict__ row_start, const int* __restrict__ col_sorted,
    const float* __restrict__ vals_sorted, const void* __restrict__ xsrc,
    const float* __restrict__ biases, float* __restrict__ out,
    int n_nodes, int batch, int size) {
  int nx = gridDim.x;
  int bx = blockIdx.x;
  // bijective XCD swizzle (m204): consecutive quads on same XCD
  int q = nx >> 3, rem = nx & 7, xcd = bx & 7, local = bx >> 3;
  int rq = (xcd < rem ? xcd * (q + 1) : rem * (q + 1) + (xcd - rem) * q) + local;
  int b = blockIdx.y * blockDim.x + threadIdx.x;
  if (b >= batch) return;
  int r0 = rq * 4;

  float acc[4][4];
#pragma unroll
  for (int i = 0; i < 4; ++i)
#pragma unroll
    for (int j = 0; j < 4; ++j) acc[i][j] = 0.f;

#pragma unroll
  for (int rr = 0; rr < 4; ++rr) {
    int r = r0 + rr;
    if (r >= n_nodes) break;
    int s = row_start[r];
    int e = row_start[r + 1];
    for (int p = s; p < e; ++p) {
      int c = col_sorted[p];
      float x0, x1, x2, x3;
      if (MODE == 0) {
        const unsigned short* xb = (const unsigned short*)xsrc;
        uint2 u = *(const uint2*)&xb[((size_t)c * batch + b) * 4];
        x0 = bf_lo(u.x); x1 = bf_hi(u.x); x2 = bf_lo(u.y); x3 = bf_hi(u.y);
      } else {
        const float* xf = (const float*)xsrc;
        float4 xv = *(const float4*)&xf[(size_t)b * size + (c << 2)];
        x0 = xv.x; x1 = xv.y; x2 = xv.z; x3 = xv.w;
      }
      const float* V = vals_sorted + (size_t)p * 16;
      acc[rr][0] += V[0] * x0 + V[1] * x1 + V[2] * x2 + V[3] * x3;
      acc[rr][1] += V[4] * x0 + V[5] * x1 + V[6] * x2 + V[7] * x3;
      acc[rr][2] += V[8] * x0 + V[9] * x1 + V[10] * x2 + V[11] * x3;
      acc[rr][3] += V[12] * x0 + V[13] * x1 + V[14] * x2 + V[15] * x3;
    }
  }
#pragma unroll
  for (int rr = 0; rr < 4; ++rr) {
    int r = r0 + rr;
    if (r >= n_nodes) break;
    float4 bias = *(const float4*)&biases[r << 2];
    float4 o = make_float4(acc[rr][0] + bias.x, acc[rr][1] + bias.y,
                           acc[rr][2] + bias.z, acc[rr][3] + bias.w);
    *(float4*)&out[(size_t)b * size + (r << 2)] = o;
  }
}

// Last-resort fallback (tiny ws)
__global__ void bias_init_kernel(float* __restrict__ out, const float* __restrict__ biases,
                                 int batch, int size) {
  size_t t = (size_t)blockIdx.x * blockDim.x + threadIdx.x;
  size_t total = (size_t)batch * size;
  if (t >= total) return;
  out[t] = biases[t % size];
}

__global__ void atomic_spmm_kernel(const int* __restrict__ indices, const float* __restrict__ vals,
                                   const float* __restrict__ x, float* __restrict__ out,
                                   int nnz, int batch, int size) {
  int n = blockIdx.x;
  if (n >= nnz) return;
  int i = indices[(size_t)n * 2];
  int j = indices[(size_t)n * 2 + 1];
  float v = vals[n];
  for (int b = threadIdx.x; b < batch; b += blockDim.x) {
    atomicAdd(&out[(size_t)b * size + i], v * x[(size_t)b * size + j]);
  }
}

extern "C" void kernel_launch(void* const* d_in, const int* in_sizes, int n_in,
                              void* d_out, int out_size, void* d_ws, size_t ws_size,
                              hipStream_t stream) {
  const float* x       = (const float*)d_in[0];
  const float* values  = (const float*)d_in[1];
  const float* biases  = (const float*)d_in[2];
  const int*   indices = (const int*)d_in[3];
  float* out = (float*)d_out;

  const int size    = in_sizes[2];        // 40000
  const int nnz     = in_sizes[1];        // 5,120,000
  const int batch   = in_sizes[0] / size; // 1024
  const int E       = nnz / 16;           // 320,000
  const int n_nodes = size / 4;           // 10,000

  // ---- workspace layout ----
  char* ws = (char*)d_ws;
  size_t off = 0;
  int* cnt = (int*)(ws + off);        off += (size_t)n_nodes * 4;
  int* cursor = (int*)(ws + off);     off += (size_t)n_nodes * 4;
  int* row_start = (int*)(ws + off);  off += ((size_t)n_nodes + 1) * 4;
  off = (off + 255) & ~(size_t)255;
  int* col_sorted = (int*)(ws + off); off += (size_t)E * 4;
  off = (off + 255) & ~(size_t)255;
  int2* edge_list = (int2*)(ws + off); off += (size_t)E * 8;
  off = (off + 255) & ~(size_t)255;
  float* vals_sorted = (float*)(ws + off); off += (size_t)E * 64;
  off = (off + 255) & ~(size_t)255;
  size_t need_csr = off;
  unsigned short* xb = (unsigned short*)(ws + off);
  off += (size_t)size * batch * 2;  // packed bf16
  size_t need_full = off;

  const int n_quads = (n_nodes + 3) / 4;

  if (ws_size >= need_csr) {
    hipMemsetAsync(cnt, 0, (size_t)2 * n_nodes * 4, stream);
    hist_kernel<<<(E + 255) / 256, 256, 0, stream>>>(indices, cnt, E);
    scan_kernel<<<1, 1024, 0, stream>>>(cnt, row_start, n_nodes);
    scatter_kernel<<<(E + 255) / 256, 256, 0, stream>>>(indices, row_start, cursor, edge_list, E);
    reorder_kernel<<<((size_t)E * 16 + 255) / 256, 256, 0, stream>>>(edge_list, values, vals_sorted, col_sorted, E);

    dim3 grid(n_quads, (batch + 255) / 256);
    if (ws_size >= need_full) {
      pack_bf16_kernel<<<dim3((size + 63) / 64, (batch + 63) / 64), 256, 0, stream>>>(
          x, xb, batch, size);
      spmm_kernel<0><<<grid, 256, 0, stream>>>(row_start, col_sorted, vals_sorted, xb,
                                               biases, out, n_nodes, batch, size);
    } else {
      spmm_kernel<1><<<grid, 256, 0, stream>>>(row_start, col_sorted, vals_sorted, x,
                                               biases, out, n_nodes, batch, size);
    }
  } else {
    size_t total = (size_t)batch * size;
    bias_init_kernel<<<(total + 255) / 256, 256, 0, stream>>>(out, biases, batch, size);
    atomic_spmm_kernel<<<nnz, 256, 0, stream>>>(indices, values, x, out, nnz, batch, size);
  }
}

// Round 3
// 457.425 us; speedup vs baseline: 2.0071x; 1.1775x over previous
//
#include <hip/hip_runtime.h>

// y[b, i] = sum v * x[b, j] + biases[i]
// 320k edges, each a dense 4x4 block at (4r, 4c); values row-major per edge.
// Round 3: fp16 x and V with v_dot2_f32_f16, 4-edge unroll (MLP), XCD
// batch-window pinning via blockIdx%8.

typedef _Float16 h2_t __attribute__((ext_vector_type(2)));

__device__ __forceinline__ h2_t as_h2(unsigned u) {
  union { unsigned u; h2_t h; } v; v.u = u; return v.h;
}

__device__ __forceinline__ float fdot2(h2_t a, h2_t b, float c) {
#if __has_builtin(__builtin_amdgcn_fdot2)
  return __builtin_amdgcn_fdot2(a, b, c, false);
#else
  return c + (float)a.x * (float)b.x + (float)a.y * (float)b.y;
#endif
}

__global__ void hist_kernel(const int* __restrict__ indices, int* __restrict__ cnt, int E) {
  int e = blockIdx.x * blockDim.x + threadIdx.x;
  if (e >= E) return;
  int bi = indices[(size_t)e * 32];
  atomicAdd(&cnt[bi >> 2], 1);
}

__global__ void scan_kernel(const int* __restrict__ cnt, int* __restrict__ row_start, int n) {
  __shared__ int buf[1024];
  __shared__ int carry_s;
  int t = threadIdx.x;
  if (t == 0) { carry_s = 0; row_start[0] = 0; }
  __syncthreads();
  for (int base = 0; base < n; base += 1024) {
    int v = (base + t < n) ? cnt[base + t] : 0;
    buf[t] = v;
    __syncthreads();
    for (int off = 1; off < 1024; off <<= 1) {
      int add = (t >= off) ? buf[t - off] : 0;
      __syncthreads();
      buf[t] += add;
      __syncthreads();
    }
    if (base + t < n) row_start[base + t + 1] = buf[t] + carry_s;
    __syncthreads();
    if (t == 0) carry_s += buf[1023];
    __syncthreads();
  }
}

__global__ void scatter_kernel(const int* __restrict__ indices, const int* __restrict__ row_start,
                               int* __restrict__ cursor, int2* __restrict__ edge_list, int E) {
  int e = blockIdx.x * blockDim.x + threadIdx.x;
  if (e >= E) return;
  int bi = indices[(size_t)e * 32];
  int bj = indices[(size_t)e * 32 + 1];
  int r = bi >> 2, c = bj >> 2;
  int pos = atomicAdd(&cursor[r], 1);
  edge_list[row_start[r] + pos] = make_int2(c, e);
}

// vals (fp32, edge-major 4x4 row-major) -> vals_h (fp16, CSR order)
__global__ void reorder_kernel(const int2* __restrict__ edge_list, const float* __restrict__ vals,
                               _Float16* __restrict__ vals_h, int* __restrict__ col_sorted, int E) {
  int tid = blockIdx.x * blockDim.x + threadIdx.x;
  int p = tid >> 4;
  int i = tid & 15;
  if (p >= E) return;
  int2 ce = edge_list[p];
  vals_h[(size_t)p * 16 + i] = (_Float16)vals[(size_t)ce.y * 16 + i];
  if (i == 0) col_sorted[p] = ce.x;
}

// x[b][4c+k] (fp32) -> xh[((c*batch)+b)*4 + k] (fp16 packed per node)
__global__ void pack_fp16_kernel(const float* __restrict__ in, uint2* __restrict__ out,
                                 int batch, int size) {
  __shared__ float tile[64][65];
  int c0 = blockIdx.x * 64;  // column (size dim) base
  int b0 = blockIdx.y * 64;  // batch base
  int tx = threadIdx.x & 63, ty = threadIdx.x >> 6;
#pragma unroll
  for (int k = 0; k < 64; k += 4) {
    int b = b0 + ty + k, c = c0 + tx;
    if (b < batch && c < size) tile[ty + k][tx] = in[(size_t)b * size + c];
  }
  __syncthreads();
#pragma unroll
  for (int it = 0; it < 4; ++it) {
    int idx = it * 256 + threadIdx.x;
    int cn_local = idx >> 6;  // 0..15
    int bl = idx & 63;
    int c_node = (c0 >> 2) + cn_local;
    int b = b0 + bl;
    if (b < batch && (c_node * 4 + 3) < size) {
      union { _Float16 h[4]; uint2 u; } cv;
      cv.h[0] = (_Float16)tile[bl][cn_local * 4 + 0];
      cv.h[1] = (_Float16)tile[bl][cn_local * 4 + 1];
      cv.h[2] = (_Float16)tile[bl][cn_local * 4 + 2];
      cv.h[3] = (_Float16)tile[bl][cn_local * 4 + 3];
      out[(size_t)c_node * batch + b] = cv.u;
    }
  }
}

__device__ __forceinline__ void edge_acc(const _Float16* __restrict__ vh, size_t p,
                                         uint2 xu, float* __restrict__ acc) {
  uint4 a = *(const uint4*)(vh + p * 16);
  uint4 c = *(const uint4*)(vh + p * 16 + 8);
  h2_t x01 = as_h2(xu.x), x23 = as_h2(xu.y);
  acc[0] = fdot2(as_h2(a.x), x01, acc[0]);
  acc[0] = fdot2(as_h2(a.y), x23, acc[0]);
  acc[1] = fdot2(as_h2(a.z), x01, acc[1]);
  acc[1] = fdot2(as_h2(a.w), x23, acc[1]);
  acc[2] = fdot2(as_h2(c.x), x01, acc[2]);
  acc[2] = fdot2(as_h2(c.y), x23, acc[2]);
  acc[3] = fdot2(as_h2(c.z), x01, acc[3]);
  acc[3] = fdot2(as_h2(c.w), x23, acc[3]);
}

// Block = (quad-pair, slot). slot = blockIdx&7 -> XCD (empirical round-robin)
// and also selects a 128-wide batch window -> per-XCD hot x-slice halves.
// threads: t>>7 picks quad within pair, t&127 is batch lane in window.
__global__ __launch_bounds__(256) void spmm_kernel(
    const int* __restrict__ row_start, const int* __restrict__ col_sorted,
    const _Float16* __restrict__ vals_h, const uint2* __restrict__ xh,
    const float* __restrict__ biases, float* __restrict__ out,
    int n_nodes, int batch, int size) {
  int id = blockIdx.x;
  int slot = id & 7;
  int qp = id >> 3;
  int t = threadIdx.x;
  int quad = qp * 2 + (t >> 7);
  if (quad * 4 >= n_nodes) return;
  int nw = (batch + 7) >> 3;  // window size

  for (int bl = (t & 127); bl < nw; bl += 128) {
    int b = slot * nw + bl;
    if (b >= batch) break;

    float acc[4][4];
#pragma unroll
    for (int i = 0; i < 16; ++i) ((float*)acc)[i] = 0.f;

#pragma unroll
    for (int rr = 0; rr < 4; ++rr) {
      int r = quad * 4 + rr;
      if (r >= n_nodes) break;
      int s = __builtin_amdgcn_readfirstlane(row_start[r]);
      int e = __builtin_amdgcn_readfirstlane(row_start[r + 1]);
      int p = s;
      for (; p + 3 < e; p += 4) {
        int c0 = col_sorted[p];
        int c1 = col_sorted[p + 1];
        int c2 = col_sorted[p + 2];
        int c3 = col_sorted[p + 3];
        uint2 x0 = xh[(size_t)c0 * batch + b];
        uint2 x1 = xh[(size_t)c1 * batch + b];
        uint2 x2 = xh[(size_t)c2 * batch + b];
        uint2 x3 = xh[(size_t)c3 * batch + b];
        edge_acc(vals_h, (size_t)p,     x0, acc[rr]);
        edge_acc(vals_h, (size_t)p + 1, x1, acc[rr]);
        edge_acc(vals_h, (size_t)p + 2, x2, acc[rr]);
        edge_acc(vals_h, (size_t)p + 3, x3, acc[rr]);
      }
      for (; p < e; ++p) {
        int c = col_sorted[p];
        uint2 xu = xh[(size_t)c * batch + b];
        edge_acc(vals_h, (size_t)p, xu, acc[rr]);
      }
    }

#pragma unroll
    for (int rr = 0; rr < 4; ++rr) {
      int r = quad * 4 + rr;
      if (r >= n_nodes) break;
      float4 bias = *(const float4*)&biases[r << 2];
      float4 o = make_float4(acc[rr][0] + bias.x, acc[rr][1] + bias.y,
                             acc[rr][2] + bias.z, acc[rr][3] + bias.w);
      *(float4*)&out[(size_t)b * size + (r << 2)] = o;
    }
  }
}

// Fallback when ws can't hold xh: gather fp32 x directly, fp16 V.
__global__ __launch_bounds__(256) void spmm_fb_kernel(
    const int* __restrict__ row_start, const int* __restrict__ col_sorted,
    const _Float16* __restrict__ vals_h, const float* __restrict__ x,
    const float* __restrict__ biases, float* __restrict__ out,
    int n_nodes, int batch, int size) {
  int quad = blockIdx.x;
  int b = blockIdx.y * blockDim.x + threadIdx.x;
  if (b >= batch || quad * 4 >= n_nodes) return;
  float acc[4][4];
#pragma unroll
  for (int i = 0; i < 16; ++i) ((float*)acc)[i] = 0.f;
#pragma unroll
  for (int rr = 0; rr < 4; ++rr) {
    int r = quad * 4 + rr;
    if (r >= n_nodes) break;
    int s = row_start[r], e = row_start[r + 1];
    for (int p = s; p < e; ++p) {
      int c = col_sorted[p];
      float4 xv = *(const float4*)&x[(size_t)b * size + (c << 2)];
      const _Float16* V = vals_h + (size_t)p * 16;
#pragma unroll
      for (int i = 0; i < 4; ++i) {
        acc[rr][i] += (float)V[i * 4 + 0] * xv.x + (float)V[i * 4 + 1] * xv.y +
                      (float)V[i * 4 + 2] * xv.z + (float)V[i * 4 + 3] * xv.w;
      }
    }
  }
#pragma unroll
  for (int rr = 0; rr < 4; ++rr) {
    int r = quad * 4 + rr;
    if (r >= n_nodes) break;
    float4 bias = *(const float4*)&biases[r << 2];
    float4 o = make_float4(acc[rr][0] + bias.x, acc[rr][1] + bias.y,
                           acc[rr][2] + bias.z, acc[rr][3] + bias.w);
    *(float4*)&out[(size_t)b * size + (r << 2)] = o;
  }
}

// Last-resort fallback (tiny ws)
__global__ void bias_init_kernel(float* __restrict__ out, const float* __restrict__ biases,
                                 int batch, int size) {
  size_t t = (size_t)blockIdx.x * blockDim.x + threadIdx.x;
  size_t total = (size_t)batch * size;
  if (t >= total) return;
  out[t] = biases[t % size];
}

__global__ void atomic_spmm_kernel(const int* __restrict__ indices, const float* __restrict__ vals,
                                   const float* __restrict__ x, float* __restrict__ out,
                                   int nnz, int batch, int size) {
  int n = blockIdx.x;
  if (n >= nnz) return;
  int i = indices[(size_t)n * 2];
  int j = indices[(size_t)n * 2 + 1];
  float v = vals[n];
  for (int b = threadIdx.x; b < batch; b += blockDim.x) {
    atomicAdd(&out[(size_t)b * size + i], v * x[(size_t)b * size + j]);
  }
}

extern "C" void kernel_launch(void* const* d_in, const int* in_sizes, int n_in,
                              void* d_out, int out_size, void* d_ws, size_t ws_size,
                              hipStream_t stream) {
  const float* x       = (const float*)d_in[0];
  const float* values  = (const float*)d_in[1];
  const float* biases  = (const float*)d_in[2];
  const int*   indices = (const int*)d_in[3];
  float* out = (float*)d_out;

  const int size    = in_sizes[2];        // 40000
  const int nnz     = in_sizes[1];        // 5,120,000
  const int batch   = in_sizes[0] / size; // 1024
  const int E       = nnz / 16;           // 320,000
  const int n_nodes = size / 4;           // 10,000

  // ---- workspace layout ----
  char* ws = (char*)d_ws;
  size_t off = 0;
  int* cnt = (int*)(ws + off);        off += (size_t)n_nodes * 4;
  int* cursor = (int*)(ws + off);     off += (size_t)n_nodes * 4;
  int* row_start = (int*)(ws + off);  off += ((size_t)n_nodes + 1) * 4;
  off = (off + 255) & ~(size_t)255;
  int* col_sorted = (int*)(ws + off); off += (size_t)E * 4;
  off = (off + 255) & ~(size_t)255;
  int2* edge_list = (int2*)(ws + off); off += (size_t)E * 8;
  off = (off + 255) & ~(size_t)255;
  _Float16* vals_h = (_Float16*)(ws + off); off += (size_t)E * 32;
  off = (off + 255) & ~(size_t)255;
  size_t need_csr = off;
  uint2* xh = (uint2*)(ws + off);
  off += (size_t)(size / 4) * batch * 8;  // fp16 packed: n_nodes*batch*8B
  size_t need_full = off;

  const int n_quads = (n_nodes + 3) / 4;

  if (ws_size >= need_csr) {
    hipMemsetAsync(cnt, 0, (size_t)2 * n_nodes * 4, stream);
    hist_kernel<<<(E + 255) / 256, 256, 0, stream>>>(indices, cnt, E);
    scan_kernel<<<1, 1024, 0, stream>>>(cnt, row_start, n_nodes);
    scatter_kernel<<<(E + 255) / 256, 256, 0, stream>>>(indices, row_start, cursor, edge_list, E);
    reorder_kernel<<<((size_t)E * 16 + 255) / 256, 256, 0, stream>>>(edge_list, values, vals_h, col_sorted, E);

    if (ws_size >= need_full) {
      pack_fp16_kernel<<<dim3((size + 63) / 64, (batch + 63) / 64), 256, 0, stream>>>(
          x, xh, batch, size);
      int npairs = (n_quads + 1) / 2;
      spmm_kernel<<<npairs * 8, 256, 0, stream>>>(row_start, col_sorted, vals_h, xh,
                                                  biases, out, n_nodes, batch, size);
    } else {
      dim3 grid(n_quads, (batch + 255) / 256);
      spmm_fb_kernel<<<grid, 256, 0, stream>>>(row_start, col_sorted, vals_h, x,
                                               biases, out, n_nodes, batch, size);
    }
  } else {
    size_t total = (size_t)batch * size;
    bias_init_kernel<<<(total + 255) / 256, 256, 0, stream>>>(out, biases, batch, size);
    atomic_spmm_kernel<<<nnz, 256, 0, stream>>>(indices, values, x, out, nnz, batch, size);
  }
}